// Round 9
// baseline (289.722 us; speedup 1.0000x reference)
//
#include <hip/hip_runtime.h>
#include <hip/hip_bf16.h>
#include <math.h>

#define N_FEAT 128
#define H1 64
#define H2 2
#define BSHIFT 9                  // 512 nodes per bucket
#define BWID (1 << BSHIFT)
#define EPB 4096                  // edges per chunk in k_bin (782 blocks)
#define GR 32                     // rows per gemm1 block
#define CAP 18432                 // per-bucket edge capacity (mean 16384, ~16 sigma)

typedef unsigned long long u64;
typedef unsigned int u32;

// bf16 helpers: RNE pack, and unpack of a (lo,hi) bf16 pair stored in a u32
__device__ __forceinline__ unsigned short f2bf(float f) {
    u32 u = __float_as_uint(f);
    u += 0x7fff + ((u >> 16) & 1);
    return (unsigned short)(u >> 16);
}
__device__ __forceinline__ float bf_lo(u32 v) { return __uint_as_float(v << 16); }
__device__ __forceinline__ float bf_hi(u32 v) { return __uint_as_float(v & 0xffff0000u); }

__device__ __forceinline__ int load_idx(const void* E, size_t i, int is64) {
    if (is64) return (int)((const long long*)E)[i];
    return ((const int*)E)[i];
}

// Inline edge-width detect: int64 values < 1e6 read as u64 stay small; int32
// pairs read as u64 are huge unless the odd element is 0 (p ~ 1e-20 for 4).
__device__ __forceinline__ int detect_is64(const void* E) {
    const u64* E64 = (const u64*)E;
    return (E64[0] <= 1000000ULL) && (E64[1] <= 1000000ULL) &&
           (E64[2] <= 1000000ULL) && (E64[3] <= 1000000ULL);
}

// ---------------------------------------------------------------------------
// Bin edges by dst bucket into padded per-bucket windows:
// packed[b*CAP + pos] = (dst_local << 17) | src. One pass over E; gcur[b]
// ends up holding bucket b's edge count. EPB=4096 -> 782 blocks (3/CU) for
// latency hiding; ~16-edge (64 B) contiguous write runs.
// ---------------------------------------------------------------------------
__global__ __launch_bounds__(256) void k_bin(const void* __restrict__ E, size_t nE,
                                             u32* __restrict__ gcur,
                                             u32* __restrict__ packed) {
    __shared__ u32 hist[256], lbase[256], lcur[256];
    __shared__ int s_is64;
    int tid = threadIdx.x;
    hist[tid] = 0;
    if (tid == 0) s_is64 = detect_is64(E);
    __syncthreads();
    int is64 = s_is64;
    size_t e0 = (size_t)blockIdx.x * EPB;
    int cnt = (int)min((size_t)EPB, nE - e0);
    for (int k = tid; k < cnt; k += 256) {
        int d = load_idx(E, nE + e0 + k, is64);
        atomicAdd(&hist[d >> BSHIFT], 1u);
    }
    __syncthreads();
    u32 h = hist[tid];
    lbase[tid] = h ? atomicAdd(&gcur[tid], h) : 0u;
    lcur[tid] = 0u;
    __syncthreads();
    for (int k = tid; k < cnt; k += 256) {
        int s = load_idx(E, e0 + k, is64);
        int d = load_idx(E, nE + e0 + k, is64);
        int b = d >> BSHIFT;
        u32 r = lbase[b] + atomicAdd(&lcur[b], 1u);
        if (r < CAP)   // overflow guard (p ~ 1e-40): drop rather than corrupt
            packed[(size_t)b * CAP + r] = ((u32)(d & (BWID - 1)) << 17) | (u32)s;
    }
}

// ---------------------------------------------------------------------------
// Per-bucket CSR build inside the bucket's padded window. One block per
// bucket; emits rp[node] (start), rend[node] (end), dinv[node] coalesced.
// Wave-shuffle scan, 1 barrier.
// ---------------------------------------------------------------------------
__global__ __launch_bounds__(512) void k_csr(const u32* __restrict__ packed,
                                             const u32* __restrict__ gcur,
                                             int* __restrict__ rp,
                                             int* __restrict__ rend,
                                             float* __restrict__ dinv,
                                             int* __restrict__ col, int N) {
    __shared__ int cnt[BWID];
    __shared__ int cur[BWID];
    __shared__ int wsum[8];
    int tid = threadIdx.x;
    int lane = tid & 63, wv = tid >> 6;
    int b = blockIdx.x;
    cnt[tid] = 0;
    __syncthreads();
    int e0 = b * CAP;
    int e1 = e0 + min((int)gcur[b], CAP);
    for (int e = e0 + tid; e < e1; e += BWID)
        atomicAdd(&cnt[packed[e] >> 17], 1);
    __syncthreads();
    int own = cnt[tid];
    int v = own;
#pragma unroll
    for (int off = 1; off < 64; off <<= 1) {
        int t = __shfl_up(v, off);
        if (lane >= off) v += t;
    }
    if (lane == 63) wsum[wv] = v;
    __syncthreads();
    int add = 0;
#pragma unroll
    for (int w = 0; w < 8; ++w) add += (w < wv) ? wsum[w] : 0;
    int excl = v + add - own;
    int node = b * BWID + tid;
    if (node < N) {
        rp[node] = e0 + excl;
        rend[node] = e0 + excl + own;
        dinv[node] = rsqrtf((float)(own + 1));
    }
    cur[tid] = excl;
    __syncthreads();
    for (int e = e0 + tid; e < e1; e += BWID) {
        u32 p = packed[e];
        int pos = e0 + atomicAdd(&cur[p >> 17], 1);
        col[pos] = (int)(p & 0x1FFFF);
    }
}

// ---------------------------------------------------------------------------
// GEMM1: h1b[row][c] = bf16( (x[row] @ W1[:,c]) * dinv[row] ).
// Split-K W staging: W held as two 16 KB halves -> total LDS 32 KB ->
// 5 blocks/CU (vs 3 at 48 KB). x-tile (16 KB) staged once. Inner loop is
// LDS-broadcast + FMA; occupancy now hides ds_read latency.
// ---------------------------------------------------------------------------
__global__ __launch_bounds__(256) void k_gemm1(const float* __restrict__ x,
                                               const float* __restrict__ W1,
                                               const float* __restrict__ dinv,
                                               unsigned short* __restrict__ h1b, int N) {
    __shared__ float Ws[64 * H1];       // 16 KB: half of W1, rows [kb, kb+64)
    __shared__ float Xs[GR * N_FEAT];   // 16 KB
    int tid = threadIdx.x;
    int row_base = blockIdx.x * GR;
    int nrow = min(GR, N - row_base);
    const float4* xg = (const float4*)(x + (size_t)row_base * N_FEAT);
    int nf4 = nrow * (N_FEAT / 4);
    for (int t = tid; t < nf4; t += 256)
        ((float4*)Xs)[t] = xg[t];

    int lane = tid & 63, wv = tid >> 6;
    int r0 = wv * 8;
    const float4* Xs4 = (const float4*)Xs;
    float acc[8] = {0.f, 0.f, 0.f, 0.f, 0.f, 0.f, 0.f, 0.f};

#pragma unroll
    for (int half = 0; half < 2; ++half) {
        __syncthreads();   // (1st iter: covers x staging; later: Ws readers done)
        for (int t = tid; t < 64 * H1 / 4; t += 256)
            ((float4*)Ws)[t] = ((const float4*)(W1 + half * 64 * H1))[t];
        __syncthreads();
        int kb = half * 16;   // float4-index base into the row
#pragma unroll 2
        for (int kk = 0; kk < 16; ++kk) {
            float w0 = Ws[(4 * kk + 0) * H1 + lane];
            float w1 = Ws[(4 * kk + 1) * H1 + lane];
            float w2 = Ws[(4 * kk + 2) * H1 + lane];
            float w3 = Ws[(4 * kk + 3) * H1 + lane];
#pragma unroll
            for (int r = 0; r < 8; ++r) {
                float4 xv = Xs4[(r0 + r) * (N_FEAT / 4) + kb + kk];
                acc[r] = fmaf(xv.x, w0, fmaf(xv.y, w1, fmaf(xv.z, w2, fmaf(xv.w, w3, acc[r]))));
            }
        }
    }
#pragma unroll
    for (int r = 0; r < 8; ++r) {
        int row = row_base + r0 + r;
        if (row < N) h1b[(size_t)row * H1 + lane] = f2bf(acc[r] * dinv[row]);
    }
}

// ---------------------------------------------------------------------------
// Agg1 + bias + relu + W2 proj. 8-lane GROUP per node (8 nodes per wave).
// Lane c4 = L&7 owns channels [8*c4, 8*c4+8) as uint4 = 16 B; the group's
// 8 lanes cover one 128 B h1 row per gather. Per-group register accumulation
// -> no cross-group butterflies; epilogue amortized over 8 nodes per wave.
// x4 unroll = 4 row-gathers in flight per group.
// ---------------------------------------------------------------------------
__global__ __launch_bounds__(256) void k_agg1(const uint4* __restrict__ h1q,
                                              const int* __restrict__ rp,
                                              const int* __restrict__ rend,
                                              const int* __restrict__ col,
                                              const float* __restrict__ dinv,
                                              const float* __restrict__ b1,
                                              const float* __restrict__ W2,
                                              float2* __restrict__ h2s, int N) {
    int tid = threadIdx.x;
    int lane = tid & 63, wv = tid >> 6;
    int g = lane >> 3;        // group (node slot) within wave
    int c4 = lane & 7;        // quad index -> channels [8*c4, 8*c4+8)
    int node = blockIdx.x * 32 + wv * 8 + g;
    if (node >= N) return;

    float acc[8] = {0.f, 0.f, 0.f, 0.f, 0.f, 0.f, 0.f, 0.f};
    {   // self loop (pre-scaled)
        uint4 v = h1q[(size_t)node * 8 + c4];
        acc[0] += bf_lo(v.x); acc[1] += bf_hi(v.x);
        acc[2] += bf_lo(v.y); acc[3] += bf_hi(v.y);
        acc[4] += bf_lo(v.z); acc[5] += bf_hi(v.z);
        acc[6] += bf_lo(v.w); acc[7] += bf_hi(v.w);
    }
    int e = rp[node], e1 = rend[node];
    for (; e + 3 < e1; e += 4) {
        int s0 = col[e + 0];
        int s1 = col[e + 1];
        int s2 = col[e + 2];
        int s3 = col[e + 3];
        uint4 v0 = h1q[(size_t)s0 * 8 + c4];
        uint4 v1 = h1q[(size_t)s1 * 8 + c4];
        uint4 v2 = h1q[(size_t)s2 * 8 + c4];
        uint4 v3 = h1q[(size_t)s3 * 8 + c4];
        acc[0] += bf_lo(v0.x) + bf_lo(v1.x) + bf_lo(v2.x) + bf_lo(v3.x);
        acc[1] += bf_hi(v0.x) + bf_hi(v1.x) + bf_hi(v2.x) + bf_hi(v3.x);
        acc[2] += bf_lo(v0.y) + bf_lo(v1.y) + bf_lo(v2.y) + bf_lo(v3.y);
        acc[3] += bf_hi(v0.y) + bf_hi(v1.y) + bf_hi(v2.y) + bf_hi(v3.y);
        acc[4] += bf_lo(v0.z) + bf_lo(v1.z) + bf_lo(v2.z) + bf_lo(v3.z);
        acc[5] += bf_hi(v0.z) + bf_hi(v1.z) + bf_hi(v2.z) + bf_hi(v3.z);
        acc[6] += bf_lo(v0.w) + bf_lo(v1.w) + bf_lo(v2.w) + bf_lo(v3.w);
        acc[7] += bf_hi(v0.w) + bf_hi(v1.w) + bf_hi(v2.w) + bf_hi(v3.w);
    }
    for (; e < e1; ++e) {
        int s = col[e];
        uint4 v = h1q[(size_t)s * 8 + c4];
        acc[0] += bf_lo(v.x); acc[1] += bf_hi(v.x);
        acc[2] += bf_lo(v.y); acc[3] += bf_hi(v.y);
        acc[4] += bf_lo(v.z); acc[5] += bf_hi(v.z);
        acc[6] += bf_lo(v.w); acc[7] += bf_hi(v.w);
    }

    float di = dinv[node];
    float4 bA = ((const float4*)b1)[c4 * 2 + 0];
    float4 bB = ((const float4*)b1)[c4 * 2 + 1];
    float vch[8];
    vch[0] = fmaxf(fmaf(di, acc[0], bA.x), 0.f);
    vch[1] = fmaxf(fmaf(di, acc[1], bA.y), 0.f);
    vch[2] = fmaxf(fmaf(di, acc[2], bA.z), 0.f);
    vch[3] = fmaxf(fmaf(di, acc[3], bA.w), 0.f);
    vch[4] = fmaxf(fmaf(di, acc[4], bB.x), 0.f);
    vch[5] = fmaxf(fmaf(di, acc[5], bB.y), 0.f);
    vch[6] = fmaxf(fmaf(di, acc[6], bB.z), 0.f);
    vch[7] = fmaxf(fmaf(di, acc[7], bB.w), 0.f);
    float p0 = 0.f, p1 = 0.f;
#pragma unroll
    for (int q = 0; q < 4; ++q) {
        // float4 = (W2[ch][0], W2[ch][1], W2[ch+1][0], W2[ch+1][1]), ch = 8*c4+2q
        float4 w = ((const float4*)W2)[c4 * 4 + q];
        p0 += vch[2 * q] * w.x + vch[2 * q + 1] * w.z;
        p1 += vch[2 * q] * w.y + vch[2 * q + 1] * w.w;
    }
    // reduce over the 8 lanes of the group (lane bits 0..2)
#pragma unroll
    for (int off = 1; off < 8; off <<= 1) {
        p0 += __shfl_xor(p0, off);
        p1 += __shfl_xor(p1, off);
    }
    if (c4 == 0) h2s[node] = make_float2(di * p0, di * p1);
}

// ---------------------------------------------------------------------------
// Agg2 + bias: out[n] = di*(h2s[n] + sum_e h2s[col[e]]) + b2.
// 16-lane group per node.
// ---------------------------------------------------------------------------
__global__ __launch_bounds__(256) void k_agg2(const float2* __restrict__ h2s,
                                              const int* __restrict__ rp,
                                              const int* __restrict__ rend,
                                              const int* __restrict__ col,
                                              const float* __restrict__ dinv,
                                              const float* __restrict__ b2,
                                              float2* __restrict__ out, int N) {
    int g = threadIdx.x >> 4;
    int lane = threadIdx.x & 15;
    int node = blockIdx.x * 16 + g;
    if (node >= N) return;
    int e0 = rp[node], e1 = rend[node];
    float a0 = 0.f, a1 = 0.f;
    for (int e = e0 + lane; e < e1; e += 16) {
        float2 v = h2s[col[e]];
        a0 += v.x;
        a1 += v.y;
    }
#pragma unroll
    for (int off = 8; off; off >>= 1) {
        a0 += __shfl_xor(a0, off, 16);
        a1 += __shfl_xor(a1, off, 16);
    }
    if (lane == 0) {
        float di = dinv[node];
        float2 self = h2s[node];
        out[node] = make_float2(fmaf(di, a0 + self.x, b2[0]),
                                fmaf(di, a1 + self.y, b2[1]));
    }
}

// ---------------------------------------------------------------------------
extern "C" void kernel_launch(void* const* d_in, const int* in_sizes, int n_in,
                              void* d_out, int out_size, void* d_ws, size_t ws_size,
                              hipStream_t stream) {
    const float* x  = (const float*)d_in[0];
    const void*  E  = d_in[1];
    const float* W1 = (const float*)d_in[2];
    const float* b1 = (const float*)d_in[3];
    const float* W2 = (const float*)d_in[4];
    const float* b2 = (const float*)d_in[5];
    float2* out = (float2*)d_out;

    const int N  = in_sizes[0] / N_FEAT;        // 100000 (< 2^17 for u32 pack)
    const int nE = in_sizes[1] / 2;             // 3200000
    const int NB = (N + BWID - 1) / BWID;       // 196

    char* ws = (char*)d_ws;
    size_t off = 0;
    auto alloc = [&](size_t bytes) -> void* {
        void* p = ws + off;
        off = (off + bytes + 255) & ~(size_t)255;
        return p;
    };
    u32*            gcur   = (u32*)alloc((size_t)NB * 4);
    int*            rp     = (int*)alloc((size_t)N * 4);
    int*            rend   = (int*)alloc((size_t)N * 4);
    float*          dinv   = (float*)alloc((size_t)N * 4);
    int*            col    = (int*)alloc((size_t)NB * CAP * 4);
    u32*            packed = (u32*)alloc((size_t)NB * CAP * 4);
    unsigned short* h1b    = (unsigned short*)alloc((size_t)N * H1 * 2);
    float2*         h2s    = (float2*)alloc((size_t)N * 8);

    hipMemsetAsync(gcur, 0, (size_t)NB * 4, stream);

    const int cgrid = (nE + EPB - 1) / EPB;     // 782

    k_bin<<<cgrid, 256, 0, stream>>>(E, (size_t)nE, gcur, packed);
    k_csr<<<NB, BWID, 0, stream>>>(packed, gcur, rp, rend, dinv, col, N);
    k_gemm1<<<(N + GR - 1) / GR, 256, 0, stream>>>(x, W1, dinv, h1b, N);
    k_agg1<<<(N + 31) / 32, 256, 0, stream>>>((const uint4*)h1b, rp, rend, col, dinv, b1, W2, h2s, N);
    k_agg2<<<(N + 15) / 16, 256, 0, stream>>>(h2s, rp, rend, col, dinv, b2, out, N);
}